// Round 6
// baseline (64.912 us; speedup 1.0000x reference)
//
#include <hip/hip_runtime.h>
#include <stdint.h>

#define NN 200000
#define DEG 32
#define BB 16384
#define DD 128
#define HH 128
#define BM 16

typedef __attribute__((ext_vector_type(8))) short bf16x8;
typedef __attribute__((ext_vector_type(4))) float f32x4;
typedef __attribute__((ext_vector_type(4))) float f4;

struct Keys { unsigned a[5][2]; unsigned l[5][2]; };

__host__ __device__ __forceinline__ unsigned rotl32(unsigned v, int r) {
  return (v << r) | (v >> (32 - r));
}

__host__ __device__ __forceinline__ void threefry2x32(
    unsigned k0, unsigned k1, unsigned x0, unsigned x1,
    unsigned* o0, unsigned* o1) {
  unsigned ks0 = k0, ks1 = k1, ks2 = k0 ^ k1 ^ 0x1BD11BDAu;
  x0 += ks0; x1 += ks1;
#define TF_RND(r) { x0 += x1; x1 = rotl32(x1, (r)); x1 ^= x0; }
  TF_RND(13) TF_RND(15) TF_RND(26) TF_RND(6)
  x0 += ks1; x1 += ks2 + 1u;
  TF_RND(17) TF_RND(29) TF_RND(16) TF_RND(24)
  x0 += ks2; x1 += ks0 + 2u;
  TF_RND(13) TF_RND(15) TF_RND(26) TF_RND(6)
  x0 += ks0; x1 += ks1 + 3u;
  TF_RND(17) TF_RND(29) TF_RND(16) TF_RND(24)
  x0 += ks1; x1 += ks2 + 4u;
  TF_RND(13) TF_RND(15) TF_RND(26) TF_RND(6)
  x0 += ks2; x1 += ks0 + 5u;
#undef TF_RND
  *o0 = x0; *o1 = x1;
}

__device__ __forceinline__ unsigned short f2bf(float x) {
  unsigned u = __float_as_uint(x);
  unsigned r = (u + 0x7fffu + ((u >> 16) & 1u)) >> 16;
  return (unsigned short)r;
}

// direct global->LDS DMA, 16B per lane (per-lane global addr, linear LDS dest)
__device__ __forceinline__ void gload_lds16(const float* g, float* l) {
  __builtin_amdgcn_global_load_lds(
      (const __attribute__((address_space(1))) void*)g,
      (__attribute__((address_space(3))) void*)l, 16, 0, 0);
}

// ---------------- walk kernel (unchanged, verified) ----------------
__global__ __launch_bounds__(256) void walk_kernel(
    const int* __restrict__ neighbors, const float* __restrict__ ew,
    const int* __restrict__ target, int* __restrict__ walks, Keys keys) {
  int lane = threadIdx.x & 63;
  int sub = lane & 31;
  int grp = (int)((blockIdx.x * 256 + threadIdx.x) >> 5);
  int wk = grp >= BB ? 1 : 0;
  int b = grp - wk * BB;

  int cur = target[b];
  if (sub == 0) walks[(size_t)grp * 6] = cur;

  const float TINY = 1.17549435e-38f;

  for (int s = 0; s < 5; ++s) {
    int nb = neighbors[(size_t)cur * DEG + sub];
    float w = ew[(size_t)cur * DEG + sub];
    unsigned j = (unsigned)b * DEG + (unsigned)sub;
    unsigned k0 = wk ? keys.l[s][0] : keys.a[s][0];
    unsigned k1 = wk ? keys.l[s][1] : keys.a[s][1];
    unsigned y0, y1;
    threefry2x32(k0, k1, 0u, j, &y0, &y1);
    unsigned bits = y0 ^ y1;
    float f = __uint_as_float((bits >> 9) | 0x3f800000u) - 1.0f;
    float u = fmaxf(TINY, f + TINY);
    float g = -logf(-logf(u));
    float v = g + logf(w);
    int idx = sub;
    #pragma unroll
    for (int off = 16; off; off >>= 1) {
      float vo = __shfl_xor(v, off);
      int io = __shfl_xor(idx, off);
      if (vo > v || (vo == v && io < idx)) { v = vo; idx = io; }
    }
    cur = __shfl(nb, (lane & 32) + idx);
    if (sub == 0) walks[(size_t)grp * 6 + s + 1] = cur;
  }
}

// ---------------- W transpose+bf16 prep: Wt[2][128 n][256 k] ----------------
__global__ __launch_bounds__(256) void prep_w(
    const float* __restrict__ Wapp, const float* __restrict__ Wloc,
    unsigned short* __restrict__ Wt) {
  int blk = blockIdx.x;
  int mat = blk >> 3;
  int k0 = (blk & 7) << 5;
  const float* W = mat ? Wloc : Wapp;
  __shared__ float tile[32][129];
  int t = threadIdx.x;
  #pragma unroll
  for (int i = 0; i < 16; ++i) {
    int idx = t + (i << 8);
    int kk = idx >> 7, n = idx & 127;
    tile[kk][n] = W[((size_t)(k0 + kk) << 7) + n];
  }
  __syncthreads();
  int n = t >> 1, h = (t & 1) << 4;
  unsigned pk[8];
  #pragma unroll
  for (int j = 0; j < 8; ++j) {
    float lo = tile[h + 2 * j][n];
    float hi = tile[h + 2 * j + 1][n];
    pk[j] = (unsigned)f2bf(lo) | ((unsigned)f2bf(hi) << 16);
  }
  unsigned short* dst = Wt + ((size_t)mat << 15) + ((size_t)n << 8) + k0 + h;
  uint4 lo4; lo4.x = pk[0]; lo4.y = pk[1]; lo4.z = pk[2]; lo4.w = pk[3];
  uint4 hi4; hi4.x = pk[4]; hi4.y = pk[5]; hi4.z = pk[6]; hi4.w = pk[7];
  reinterpret_cast<uint4*>(dst)[0] = lo4;
  reinterpret_cast<uint4*>(dst)[1] = hi4;
}

// ---- fused gather(global_load_lds) + MFMA GEMM + attention, BM=16 ----
__global__ __launch_bounds__(256, 2) void fuse4(
    const float* __restrict__ x_app, const float* __restrict__ x_loc,
    const float* __restrict__ x_time, const int* __restrict__ target,
    const int* __restrict__ walks, const unsigned short* __restrict__ Wt,
    const float* __restrict__ W_att, const float* __restrict__ b_att,
    const float* __restrict__ b_app, const float* __restrict__ b_loc,
    float* __restrict__ out) {
  // stage: 4 waves x 24 rows x 128 f32 = 48 KB (reused app then loc)
  __shared__ float stage[96][128];
  __shared__ unsigned short sA[BM][264];
  __shared__ unsigned short sL[BM][264];
  __shared__ float attT[BM];
  __shared__ float4 sRed[4][BM];

  int tid = threadIdx.x;
  int b0 = blockIdx.x * BM;
  int w = tid >> 6;                        // wave 0..3 -> targets 4w..4w+3
  int l = tid & 63;
  int h = l >> 5;                          // half-wave
  int c = l & 31;                          // 16B column slot

  // per-wave walk node ids: lane i<24 holds node for (target 4w+i/6, slot i%6)
  int myNodeA = 0, myNodeL = 0;
  if (l < 24) {
    int t4 = 4 * w + l / 6, s6 = l % 6;
    myNodeA = walks[(size_t)(b0 + t4) * 6 + s6];
    myNodeL = walks[(size_t)(BB + b0 + t4) * 6 + s6];
  }

  // ---- app phase: 12 DMA loads (2 rows each) into wave-private stage ----
  #pragma unroll
  for (int p = 0; p < 12; ++p) {
    int node = __shfl(myNodeA, 2 * p + h);
    gload_lds16(&x_app[((size_t)node << 7) + (c << 2)], &stage[w * 24 + 2 * p][0]);
  }
  asm volatile("s_waitcnt vmcnt(0)" ::: "memory");
  __builtin_amdgcn_sched_barrier(0);

  const float4 wa = *(const float4*)&W_att[4 * c];
  #pragma unroll
  for (int q = 0; q < 2; ++q) {
    int j = 2 * h + q;
    int rbase = w * 24 + j * 6;
    f4 v0 = *(const f4*)&stage[rbase][4 * c];     // slot 0 = target row
    f4 s = v0;
    #pragma unroll
    for (int s6 = 1; s6 < 6; ++s6) s += *(const f4*)&stage[rbase + s6][4 * c];
    uint2 pt, ps;
    pt.x = (unsigned)f2bf(v0.x) | ((unsigned)f2bf(v0.y) << 16);
    pt.y = (unsigned)f2bf(v0.z) | ((unsigned)f2bf(v0.w) << 16);
    ps.x = (unsigned)f2bf(s.x) | ((unsigned)f2bf(s.y) << 16);
    ps.y = (unsigned)f2bf(s.z) | ((unsigned)f2bf(s.w) << 16);
    int tj = 4 * w + j;
    *(uint2*)&sA[tj][4 * c] = pt;
    *(uint2*)&sA[tj][128 + 4 * c] = ps;
    float p0 = v0.x * wa.x + v0.y * wa.y + v0.z * wa.z + v0.w * wa.w;
    #pragma unroll
    for (int off = 16; off; off >>= 1) p0 += __shfl_xor(p0, off);
    if (c == 0) attT[tj] = p0;
  }

  // all stage reads retired before loc DMA overwrites
  asm volatile("s_waitcnt lgkmcnt(0)" ::: "memory");
  __builtin_amdgcn_sched_barrier(0);

  // ---- loc phase ----
  #pragma unroll
  for (int p = 0; p < 12; ++p) {
    int node = __shfl(myNodeL, 2 * p + h);
    gload_lds16(&x_loc[((size_t)node << 7) + (c << 2)], &stage[w * 24 + 2 * p][0]);
  }
  asm volatile("s_waitcnt vmcnt(0)" ::: "memory");
  __builtin_amdgcn_sched_barrier(0);

  #pragma unroll
  for (int q = 0; q < 2; ++q) {
    int j = 2 * h + q;
    int rbase = w * 24 + j * 6;
    f4 v0 = *(const f4*)&stage[rbase][4 * c];
    f4 s = v0;
    #pragma unroll
    for (int s6 = 1; s6 < 6; ++s6) s += *(const f4*)&stage[rbase + s6][4 * c];
    uint2 pt, ps;
    pt.x = (unsigned)f2bf(v0.x) | ((unsigned)f2bf(v0.y) << 16);
    pt.y = (unsigned)f2bf(v0.z) | ((unsigned)f2bf(v0.w) << 16);
    ps.x = (unsigned)f2bf(s.x) | ((unsigned)f2bf(s.y) << 16);
    ps.y = (unsigned)f2bf(s.z) | ((unsigned)f2bf(s.w) << 16);
    int tj = 4 * w + j;
    *(uint2*)&sL[tj][4 * c] = pt;
    *(uint2*)&sL[tj][128 + 4 * c] = ps;
  }
  __syncthreads();

  int r15 = l & 15, g = l >> 4;

  f32x4 accA[2], accL[2];
  {
    bf16x8 aF[8], lF[8];
    #pragma unroll
    for (int k = 0; k < 8; ++k) {
      aF[k] = *(const bf16x8*)&sA[r15][(k << 5) + (g << 3)];
      lF[k] = *(const bf16x8*)&sL[r15][(k << 5) + (g << 3)];
    }
    #pragma unroll
    for (int n = 0; n < 2; ++n) {
      int col = ((w << 1) + n) << 4;
      f32x4 a1 = {0.f, 0.f, 0.f, 0.f}, a2 = {0.f, 0.f, 0.f, 0.f};
      #pragma unroll
      for (int k = 0; k < 8; ++k) {
        bf16x8 bA = *(const bf16x8*)&Wt[(((size_t)col + r15) << 8) + (k << 5) + (g << 3)];
        bf16x8 bL = *(const bf16x8*)&Wt[(1 << 15) + (((size_t)col + r15) << 8) + (k << 5) + (g << 3)];
        a1 = __builtin_amdgcn_mfma_f32_16x16x32_bf16(aF[k], bA, a1, 0, 0, 0);
        a2 = __builtin_amdgcn_mfma_f32_16x16x32_bf16(lF[k], bL, a2, 0, 0, 0);
      }
      accA[n] = a1;
      accL[n] = a2;
    }
  }

  float bA[2], bL[2], wv[2];
  #pragma unroll
  for (int n = 0; n < 2; ++n) {
    int col = (((w << 1) + n) << 4) + r15;
    bA[n] = b_app[col];
    bL[n] = b_loc[col];
    wv[n] = W_att[128 + col];
  }
  float batt = b_att[0];

  int trow[4];
  #pragma unroll
  for (int r = 0; r < 4; ++r) trow[r] = target[b0 + (g << 2) + r];
  float tts[2][4];
  #pragma unroll
  for (int n = 0; n < 2; ++n)
    #pragma unroll
    for (int r = 0; r < 4; ++r)
      tts[n][r] = x_time[((size_t)trow[r] << 7) + (((w << 1) + n) << 4) + r15];

  float fa[2][4], fl[2][4];
  #pragma unroll
  for (int r = 0; r < 4; ++r) {
    float dA = 0.f, dL = 0.f, dT = 0.f;
    #pragma unroll
    for (int n = 0; n < 2; ++n) {
      fa[n][r] = fmaxf(accA[n][r] + bA[n], 0.f);
      fl[n][r] = fmaxf(accL[n][r] + bL[n], 0.f);
      dA += fa[n][r] * wv[n];
      dL += fl[n][r] * wv[n];
      dT += tts[n][r] * wv[n];
    }
    #pragma unroll
    for (int off = 1; off < 16; off <<= 1) {
      dA += __shfl_xor(dA, off);
      dL += __shfl_xor(dL, off);
      dT += __shfl_xor(dT, off);
    }
    if (r15 == 0) {
      float4 q; q.x = dA; q.y = dL; q.z = dT; q.w = 0.f;
      sRed[w][(g << 2) + r] = q;
    }
  }
  __syncthreads();

  #pragma unroll
  for (int r = 0; r < 4; ++r) {
    int row = (g << 2) + r;
    float4 q0 = sRed[0][row], q1 = sRed[1][row], q2 = sRed[2][row], q3 = sRed[3][row];
    float at = attT[row] + batt;
    float s0 = at + q0.x + q1.x + q2.x + q3.x;
    float s1 = at + q0.y + q1.y + q2.y + q3.y;
    float s2 = at + q0.z + q1.z + q2.z + q3.z;
    float m = fmaxf(s0, fmaxf(s1, s2));
    float e0 = expf(s0 - m), e1 = expf(s1 - m), e2 = expf(s2 - m);
    float inv = 1.f / (e0 + e1 + e2);
    size_t grow = (size_t)(b0 + row);
    #pragma unroll
    for (int n = 0; n < 2; ++n) {
      int col = (((w << 1) + n) << 4) + r15;
      out[(grow << 7) + col] = (e0 * fa[n][r] + e1 * fl[n][r] + e2 * tts[n][r]) * inv;
    }
  }
}

extern "C" void kernel_launch(void* const* d_in, const int* in_sizes, int n_in,
                              void* d_out, int out_size, void* d_ws, size_t ws_size,
                              hipStream_t stream) {
  (void)in_sizes; (void)n_in; (void)out_size; (void)ws_size;
  const float* x_app   = (const float*)d_in[0];
  const float* x_loc   = (const float*)d_in[1];
  const float* x_time  = (const float*)d_in[2];
  const int*   neighbors = (const int*)d_in[3];
  const float* ew      = (const float*)d_in[4];
  const int*   target  = (const int*)d_in[5];
  const float* W_app   = (const float*)d_in[6];
  const float* b_app   = (const float*)d_in[7];
  const float* W_loc   = (const float*)d_in[8];
  const float* b_loc   = (const float*)d_in[9];
  const float* W_att   = (const float*)d_in[10];
  const float* b_att   = (const float*)d_in[11];
  float* out = (float*)d_out;
  int* walks = (int*)d_ws;                           // [2][BB][6] = 786 KB
  unsigned short* Wt =
      (unsigned short*)((char*)d_ws + (size_t)2 * BB * 6 * sizeof(int)); // 128 KB

  Keys keys;
  unsigned k1a, k1b, k2a, k2b;
  threefry2x32(0u, 42u, 0u, 0u, &k1a, &k1b);
  threefry2x32(0u, 42u, 0u, 1u, &k2a, &k2b);
  for (unsigned s = 0; s < 5; ++s) {
    threefry2x32(k1a, k1b, 0u, s, &keys.a[s][0], &keys.a[s][1]);
    threefry2x32(k2a, k2b, 0u, s, &keys.l[s][0], &keys.l[s][1]);
  }

  walk_kernel<<<(2 * BB * 32) / 256, 256, 0, stream>>>(neighbors, ew, target, walks, keys);
  prep_w<<<16, 256, 0, stream>>>(W_app, W_loc, Wt);
  fuse4<<<BB / BM, 256, 0, stream>>>(x_app, x_loc, x_time, target, walks, Wt,
                                     W_att, b_att, b_app, b_loc, out);
}